// Round 6
// baseline (449.439 us; speedup 1.0000x reference)
//
#include <hip/hip_runtime.h>

// ---------------------------------------------------------------------------
// GCN encoder: out = GCNConv2( relu(GCNConv1(x)) )
// R5: GEMM BM=64 (occupancy fix). CSR build via bucketed counting sort:
// hist -> scan -> bucket-scatter -> per-bucket exact CSR (+offs+dinv).
// csr stores src only; gather recomputes w = dinv[src]*dinv[dst].
// ---------------------------------------------------------------------------

typedef __attribute__((ext_vector_type(8))) short short8;
typedef __attribute__((ext_vector_type(4))) float floatx4;
typedef _Float16 __attribute__((ext_vector_type(8))) half8v;

#define BUCK_SH 6
#define BUCK    64           // dsts per bucket

// edge_index may arrive as int64 (reference dtype) or int32 (harness contract).
__global__ void detect64_kernel(const int* __restrict__ ei, int* __restrict__ flag) {
    __shared__ int nz;
    if (threadIdx.x == 0) nz = 0;
    __syncthreads();
    if (ei[2 * threadIdx.x + 1] != 0) atomicOr(&nz, 1);
    __syncthreads();
    if (threadIdx.x == 0) *flag = (nz == 0) ? 1 : 0;
}

__device__ __forceinline__ int edge_id(const int* __restrict__ ei, int is64, long long pos) {
    return is64 ? ei[2 * pos] : ei[(int)pos];
}

// ---- bucket histogram (LDS-aggregated) ------------------------------------
__global__ void bhist_kernel(const int* __restrict__ ei, const int* __restrict__ flag,
                             int* __restrict__ bhist, int E, int NB) {
    __shared__ int h[1024];
    const int t = threadIdx.x;
    for (int i = t; i < NB; i += blockDim.x) h[i] = 0;
    __syncthreads();
    const int is64 = *flag;
    for (long long e = (long long)blockIdx.x * blockDim.x + t; e < E;
         e += (long long)gridDim.x * blockDim.x) {
        int d = edge_id(ei, is64, (long long)E + e);
        atomicAdd(&h[d >> BUCK_SH], 1);
    }
    __syncthreads();
    for (int i = t; i < NB; i += blockDim.x)
        if (h[i]) atomicAdd(&bhist[i], h[i]);
}

// ---- single-block scan of bucket histogram -> bbase[NB+1], bcur copy -------
__global__ void bscan_kernel(const int* __restrict__ bhist, int* __restrict__ bbase,
                             int* __restrict__ bcur, int NB, int E) {
    __shared__ int sm[1024];
    const int t = threadIdx.x;
    int v = (t < NB) ? bhist[t] : 0;
    sm[t] = v;
    __syncthreads();
    for (int s = 1; s < 1024; s <<= 1) {
        int u = (t >= s) ? sm[t - s] : 0;
        __syncthreads();
        sm[t] += u;
        __syncthreads();
    }
    int excl = sm[t] - v;
    if (t < NB) { bbase[t] = excl; bcur[t] = excl; }
    if (t == 0) bbase[NB] = E;
}

// ---- scatter edges into bucket regions (L2-local writes) -------------------
__global__ void bscatter_kernel(const int* __restrict__ ei, const int* __restrict__ flag,
                                int* __restrict__ bcur, int2* __restrict__ ebuf, int E) {
    long long e = (long long)blockIdx.x * blockDim.x + threadIdx.x;
    if (e >= E) return;
    const int is64 = *flag;
    int s = edge_id(ei, is64, e);
    int d = edge_id(ei, is64, (long long)E + e);
    int pos = atomicAdd(&bcur[d >> BUCK_SH], 1);
    ebuf[pos] = make_int2(s, d);
}

// ---- per-bucket exact CSR build: offs, dinv, csr(src only) -----------------
__global__ void csrbuild_kernel(const int2* __restrict__ ebuf, const int* __restrict__ bbase,
                                int* __restrict__ offs, float* __restrict__ dinv,
                                int* __restrict__ csr, int N, int NB, int E) {
    __shared__ int cnt[BUCK], exc[BUCK], cur[BUCK];
    const int b = blockIdx.x;
    const int t = threadIdx.x;
    if (t < BUCK) { cnt[t] = 0; cur[t] = 0; }
    __syncthreads();
    const int lo = bbase[b], hi = bbase[b + 1];
    for (int i = lo + t; i < hi; i += blockDim.x)
        atomicAdd(&cnt[ebuf[i].y & (BUCK - 1)], 1);
    __syncthreads();
    if (t == 0) {
        int run = 0;
        for (int l = 0; l < BUCK; ++l) { exc[l] = run; run += cnt[l]; }
    }
    __syncthreads();
    if (t < BUCK) {
        int n = b * BUCK + t;
        if (n < N) {
            offs[n] = lo + exc[t];
            dinv[n] = rsqrtf(1.0f + (float)cnt[t]);
        }
    }
    if (b == NB - 1 && t == 0) offs[N] = E;
    for (int i = lo + t; i < hi; i += blockDim.x) {
        int2 e = ebuf[i];
        int l = e.y & (BUCK - 1);
        int p = lo + exc[l] + atomicAdd(&cur[l], 1);
        csr[p] = e.x;
    }
}

// ---------------------------------------------------------------------------
// Weight pre-transform: W[K][Nc] fp32 -> Wh_t/Wl_t [Nc][K] bf16 (split hi/lo)
// ---------------------------------------------------------------------------
__device__ __forceinline__ unsigned short bf16_rne(float x) {
    unsigned u = __float_as_uint(x);
    return (unsigned short)((u + 0x7fff + ((u >> 16) & 1)) >> 16);
}

__device__ __forceinline__ void convW_one(const float* W, unsigned short* Ht,
                                          unsigned short* Lt, int K, int Nc, int idx) {
    if (idx >= K * Nc) return;
    int k = idx / Nc, n = idx % Nc;
    float a = W[idx];
    unsigned u = __float_as_uint(a);
    unsigned short hi = (unsigned short)(u >> 16);          // truncation
    float hf = __uint_as_float(u & 0xffff0000u);
    unsigned short lo = bf16_rne(a - hf);
    Ht[(long long)n * K + k] = hi;
    Lt[(long long)n * K + k] = lo;
}

__global__ void convW_kernel(const float* __restrict__ W1, unsigned short* __restrict__ H1,
                             unsigned short* __restrict__ L1, int K1, int N1, int nb1,
                             const float* __restrict__ W2, unsigned short* __restrict__ H2,
                             unsigned short* __restrict__ L2, int K2, int N2) {
    if ((int)blockIdx.x < nb1) {
        convW_one(W1, H1, L1, K1, N1, blockIdx.x * blockDim.x + threadIdx.x);
    } else {
        convW_one(W2, H2, L2, K2, N2, (blockIdx.x - nb1) * blockDim.x + threadIdx.x);
    }
}

// ---------------------------------------------------------------------------
// Split-bf16 MFMA GEMM: C[M,NCOL] = A[M,K]fp32 @ B[K,NCOL]fp32
// BM=64, 4 waves x one 16-row tile. A staged via LDS, double-buffered.
// ---------------------------------------------------------------------------
template <int NCOL, int K, typename CT>
__launch_bounds__(256)
__global__ void mfma_gemm_kernel(const float* __restrict__ A,
                                 const unsigned short* __restrict__ Bh,
                                 const unsigned short* __restrict__ Bl,
                                 CT* __restrict__ C, int M) {
    constexpr int NCB = NCOL / 16;   // 8 (GEMM1) or 4 (GEMM2)
    constexpr int BM  = 64;
    constexpr int AST = 36;          // LDS row stride in floats
    __shared__ float As[2][BM * AST];

    const int tid  = threadIdx.x;
    const int wave = tid >> 6;
    const int lane = tid & 63;
    const int n15  = lane & 15;
    const int q    = lane >> 4;
    const int row0 = blockIdx.x * BM;

    floatx4 acc[NCB];
#pragma unroll
    for (int c = 0; c < NCB; ++c) acc[c] = (floatx4){0.f, 0.f, 0.f, 0.f};

    auto stage = [&](int buf, int kc) {
#pragma unroll
        for (int it = 0; it < BM * 8 / 256; ++it) {   // BM*32 floats = BM*8 float4
            int f  = it * 256 + tid;
            int r  = f >> 3;
            int c4 = (f & 7) * 4;
            int gr = row0 + r;
            if (gr >= M) gr = M - 1;
            float4 v = *(const float4*)&A[(long long)gr * K + kc + c4];
            *(float4*)&As[buf][r * AST + c4] = v;
        }
    };

    stage(0, 0);
    __syncthreads();

    int buf = 0;
    for (int kc = 0; kc < K; kc += 32, buf ^= 1) {
        if (kc + 32 < K) stage(buf ^ 1, kc + 32);

        short8 ah, al;
        {
            const float* p = &As[buf][(wave * 16 + n15) * AST + q * 8];
            float4 a0 = *(const float4*)p;
            float4 a1 = *(const float4*)(p + 4);
            float av[8] = {a0.x, a0.y, a0.z, a0.w, a1.x, a1.y, a1.z, a1.w};
#pragma unroll
            for (int j = 0; j < 8; ++j) {
                unsigned u = __float_as_uint(av[j]);
                ah[j] = (short)(u >> 16);
                float hf = __uint_as_float(u & 0xffff0000u);
                al[j] = (short)bf16_rne(av[j] - hf);
            }
        }

#pragma unroll
        for (int cb = 0; cb < NCB; ++cb) {
            long long boff = (long long)(cb * 16 + n15) * K + kc + q * 8;
            short8 bh = *(const short8*)&Bh[boff];
            short8 bl = *(const short8*)&Bl[boff];
            acc[cb] = __builtin_amdgcn_mfma_f32_16x16x32_bf16(ah, bh, acc[cb], 0, 0, 0);
            acc[cb] = __builtin_amdgcn_mfma_f32_16x16x32_bf16(al, bh, acc[cb], 0, 0, 0);
            acc[cb] = __builtin_amdgcn_mfma_f32_16x16x32_bf16(ah, bl, acc[cb], 0, 0, 0);
        }
        __syncthreads();
    }

    // C/D layout: col = cb*16 + n15, row-in-tile = q*4 + reg
#pragma unroll
    for (int cb = 0; cb < NCB; ++cb) {
        int col = cb * 16 + n15;
#pragma unroll
        for (int r = 0; r < 4; ++r) {
            int gr = row0 + wave * 16 + q * 4 + r;
            if (gr < M) C[(long long)gr * NCOL + col] = (CT)acc[cb][r];
        }
    }
}

// ---------------------------------------------------------------------------
// Gather aggregation, fp16 h, 8 channels/lane, 8-edge unroll, w recomputed:
// out[n][:] = (h[n]*dinv[n]^2 + sum_e h[src]*dinv[src]*dinv[n]) + bias (,relu)
// ---------------------------------------------------------------------------
template <int F, int RELU>
__launch_bounds__(256)
__global__ void gatherh_kernel(const _Float16* __restrict__ h, const int* __restrict__ csr,
                               const int* __restrict__ offs, const float* __restrict__ dinv,
                               const float* __restrict__ bias, float* __restrict__ out, int N) {
    constexpr int L = F / 8;            // lanes per node
    constexpr int NPB = 256 / L;        // nodes per block
    const int n = blockIdx.x * NPB + threadIdx.x / L;
    const int c8 = (threadIdx.x % L) * 8;
    if (n >= N) return;

    const float di = dinv[n];
    half8v hs = *(const half8v*)&h[(long long)n * F + c8];
    float acc[8];
    const float sd = di * di;
#pragma unroll
    for (int j = 0; j < 8; ++j) acc[j] = (float)hs[j] * sd;

    int j = offs[n];
    const int end = offs[n + 1];
    for (; j + 7 < end; j += 8) {
        int s[8];
        float ws[8];
        half8v v[8];
#pragma unroll
        for (int u = 0; u < 8; ++u) s[u] = csr[j + u];
#pragma unroll
        for (int u = 0; u < 8; ++u) ws[u] = dinv[s[u]];
#pragma unroll
        for (int u = 0; u < 8; ++u) v[u] = *(const half8v*)&h[(long long)s[u] * F + c8];
#pragma unroll
        for (int u = 0; u < 8; ++u) {
            float w = ws[u] * di;
#pragma unroll
            for (int t = 0; t < 8; ++t) acc[t] = fmaf((float)v[u][t], w, acc[t]);
        }
    }
    for (; j < end; ++j) {
        int s = csr[j];
        float w = dinv[s] * di;
        half8v v = *(const half8v*)&h[(long long)s * F + c8];
#pragma unroll
        for (int t = 0; t < 8; ++t) acc[t] = fmaf((float)v[t], w, acc[t]);
    }

    float4 b0 = *(const float4*)&bias[c8];
    float4 b1 = *(const float4*)&bias[c8 + 4];
    float bb[8] = {b0.x, b0.y, b0.z, b0.w, b1.x, b1.y, b1.z, b1.w};
#pragma unroll
    for (int t = 0; t < 8; ++t) {
        acc[t] += bb[t];
        if (RELU) acc[t] = fmaxf(acc[t], 0.f);
    }
    float* o = &out[(long long)n * F + c8];
    *(float4*)o       = make_float4(acc[0], acc[1], acc[2], acc[3]);
    *(float4*)(o + 4) = make_float4(acc[4], acc[5], acc[6], acc[7]);
}

extern "C" void kernel_launch(void* const* d_in, const int* in_sizes, int n_in,
                              void* d_out, int out_size, void* d_ws, size_t ws_size,
                              hipStream_t stream) {
    const float* x  = (const float*)d_in[0];
    const int*   ei = (const int*)d_in[1];
    const float* W1 = (const float*)d_in[2];
    const float* b1 = (const float*)d_in[3];
    const float* W2 = (const float*)d_in[4];
    const float* b2 = (const float*)d_in[5];
    float* out = (float*)d_out;

    const int IN_CH = 256, HID = 128, OUT = 64;
    const int N = in_sizes[0] / IN_CH;     // 50000
    const int E = in_sizes[1] / 2;         // 800000
    const int NB = (N + BUCK - 1) / BUCK;  // 782 buckets

    char* w = (char*)d_ws;
    size_t off_b = 0;
    auto alloc = [&](size_t bytes) { void* p = w + off_b; off_b = (off_b + bytes + 255) & ~(size_t)255; return p; };
    int*   flag   = (int*)alloc(256);
    int*   bhist  = (int*)alloc((size_t)NB * 4);
    int*   bbase  = (int*)alloc((size_t)(NB + 1) * 4);
    int*   bcur   = (int*)alloc((size_t)NB * 4);
    int*   offs   = (int*)alloc((size_t)(N + 1) * 4);
    float* dinv   = (float*)alloc((size_t)N * 4);
    int2*  ebuf   = (int2*)alloc((size_t)E * 8);
    int*   csr    = (int*)alloc((size_t)E * 4);
    unsigned short* W1h = (unsigned short*)alloc((size_t)IN_CH * HID * 2);
    unsigned short* W1l = (unsigned short*)alloc((size_t)IN_CH * HID * 2);
    unsigned short* W2h = (unsigned short*)alloc((size_t)HID * OUT * 2);
    unsigned short* W2l = (unsigned short*)alloc((size_t)HID * OUT * 2);
    _Float16* h1  = (_Float16*)alloc((size_t)N * HID * 2); // fp16; reused as h2
    float* agg1   = (float*)alloc((size_t)N * HID * 4);    // fp32
    _Float16* h2  = h1;

    hipMemsetAsync(bhist, 0, (size_t)NB * 4, stream);

    const int T = 256;
    detect64_kernel<<<1, 256, 0, stream>>>(ei, flag);
    bhist_kernel<<<256, T, 0, stream>>>(ei, flag, bhist, E, NB);
    bscan_kernel<<<1, 1024, 0, stream>>>(bhist, bbase, bcur, NB, E);
    bscatter_kernel<<<(E + T - 1) / T, T, 0, stream>>>(ei, flag, bcur, ebuf, E);
    csrbuild_kernel<<<NB, T, 0, stream>>>(ebuf, bbase, offs, dinv, csr, N, NB, E);

    {
        int nb1 = (IN_CH * HID + T - 1) / T;
        int nb2 = (HID * OUT + T - 1) / T;
        convW_kernel<<<nb1 + nb2, T, 0, stream>>>(W1, W1h, W1l, IN_CH, HID, nb1,
                                                  W2, W2h, W2l, HID, OUT);
    }

    // GEMM1: h1[N,128](fp16) = x[N,256] @ W1
    mfma_gemm_kernel<128, 256, _Float16><<<(N + 63) / 64, 256, 0, stream>>>(x, W1h, W1l, h1, N);
    // layer-1 aggregation (fp16 gather, fused self-loop + bias + relu) -> agg1 (fp32)
    gatherh_kernel<128, 1><<<(N * 16 + 255) / 256, 256, 0, stream>>>(h1, csr, offs, dinv, b1, agg1, N);
    // GEMM2: h2[N,64](fp16) = agg1[N,128] @ W2
    mfma_gemm_kernel<64, 128, _Float16><<<(N + 63) / 64, 256, 0, stream>>>(agg1, W2h, W2l, h2, N);
    // layer-2 aggregation (fp16 gather, fused self-loop + bias) -> out (fp32)
    gatherh_kernel<64, 0><<<(N * 8 + 255) / 256, 256, 0, stream>>>(h2, csr, offs, dinv, b2, out, N);
}

// Round 7
// 287.306 us; speedup vs baseline: 1.5643x; 1.5643x over previous
//
#include <hip/hip_runtime.h>

// ---------------------------------------------------------------------------
// GCN encoder: out = GCNConv2( relu(GCNConv1(x)) )
// R6: deterministic bucketed counting-sort CSR build with ZERO global atomics
// (hist2 -> bscan2 -> scatter2 LDS-cursor -> csrbuild). Packed 4B edge recs.
// GEMM BM=64 (R5), fp16 h + 8x-unroll gathers (R4/R5).
// ---------------------------------------------------------------------------

typedef __attribute__((ext_vector_type(8))) short short8;
typedef __attribute__((ext_vector_type(4))) float floatx4;
typedef _Float16 __attribute__((ext_vector_type(8))) half8v;

#define BUCK_SH 6
#define BUCK    64           // dsts per bucket
#define NBLK    256          // blocks for hist2/scatter2

// edge_index may arrive as int64 (reference dtype) or int32 (harness contract).
__global__ void detect64_kernel(const int* __restrict__ ei, int* __restrict__ flag) {
    __shared__ int nz;
    if (threadIdx.x == 0) nz = 0;
    __syncthreads();
    if (ei[2 * threadIdx.x + 1] != 0) atomicOr(&nz, 1);
    __syncthreads();
    if (threadIdx.x == 0) *flag = (nz == 0) ? 1 : 0;
}

__device__ __forceinline__ int edge_id(const int* __restrict__ ei, int is64, long long pos) {
    return is64 ? ei[2 * pos] : ei[(int)pos];
}

// ---- per-block bucket histogram -> hist2[blk][NB] (no global atomics) ------
__global__ void hist2_kernel(const int* __restrict__ ei, const int* __restrict__ flag,
                             int* __restrict__ hist2, int E, int NB, int chunk) {
    __shared__ int h[1024];
    const int t = threadIdx.x;
    for (int i = t; i < NB; i += blockDim.x) h[i] = 0;
    __syncthreads();
    const int is64 = *flag;
    const int lo = blockIdx.x * chunk;
    const int hi = min(E, lo + chunk);
    for (int e = lo + t; e < hi; e += blockDim.x) {
        int d = edge_id(ei, is64, (long long)E + e);
        atomicAdd(&h[d >> BUCK_SH], 1);
    }
    __syncthreads();
    for (int i = t; i < NB; i += blockDim.x) hist2[(long long)blockIdx.x * NB + i] = h[i];
}

// ---- single block: column sums -> bucket scan -> bbase + start2 ------------
__global__ void bscan2_kernel(const int* __restrict__ hist2, int* __restrict__ bbase,
                              int* __restrict__ start2, int NB, int E) {
    __shared__ int sm[1024];
    const int t = threadIdx.x;           // t = bucket id
    int col = 0;
    if (t < NB)
        for (int b = 0; b < NBLK; ++b) col += hist2[(long long)b * NB + t];
    sm[t] = col;
    __syncthreads();
    for (int s = 1; s < 1024; s <<= 1) {
        int u = (t >= s) ? sm[t - s] : 0;
        __syncthreads();
        sm[t] += u;
        __syncthreads();
    }
    int excl = sm[t] - col;
    if (t < NB) {
        bbase[t] = excl;
        int run = excl;
        for (int b = 0; b < NBLK; ++b) {
            start2[(long long)b * NB + t] = run;
            run += hist2[(long long)b * NB + t];
        }
    }
    if (t == 0) bbase[NB] = E;
}

// ---- scatter: LDS cursors only, packed record src | (dlocal<<26) -----------
__global__ void scatter2_kernel(const int* __restrict__ ei, const int* __restrict__ flag,
                                const int* __restrict__ start2, unsigned* __restrict__ ebuf,
                                int E, int NB, int chunk) {
    __shared__ int hcur[1024];
    const int t = threadIdx.x;
    for (int i = t; i < NB; i += blockDim.x)
        hcur[i] = start2[(long long)blockIdx.x * NB + i];
    __syncthreads();
    const int is64 = *flag;
    const int lo = blockIdx.x * chunk;
    const int hi = min(E, lo + chunk);
    for (int e = lo + t; e < hi; e += blockDim.x) {
        int s = edge_id(ei, is64, e);
        int d = edge_id(ei, is64, (long long)E + e);
        int pos = atomicAdd(&hcur[d >> BUCK_SH], 1);
        ebuf[pos] = (unsigned)s | ((unsigned)(d & (BUCK - 1)) << 26);
    }
}

// ---- per-bucket exact CSR build: offs, dinv, csr(src only) -----------------
__global__ void csrbuild_kernel(const unsigned* __restrict__ ebuf, const int* __restrict__ bbase,
                                int* __restrict__ offs, float* __restrict__ dinv,
                                int* __restrict__ csr, int N, int NB, int E) {
    __shared__ int cnt[BUCK], exc[BUCK], cur[BUCK];
    const int b = blockIdx.x;
    const int t = threadIdx.x;
    if (t < BUCK) { cnt[t] = 0; cur[t] = 0; }
    __syncthreads();
    const int lo = bbase[b], hi = bbase[b + 1];
    for (int i = lo + t; i < hi; i += blockDim.x)
        atomicAdd(&cnt[ebuf[i] >> 26], 1);
    __syncthreads();
    if (t == 0) {
        int run = 0;
        for (int l = 0; l < BUCK; ++l) { exc[l] = run; run += cnt[l]; }
    }
    __syncthreads();
    if (t < BUCK) {
        int n = b * BUCK + t;
        if (n < N) {
            offs[n] = lo + exc[t];
            dinv[n] = rsqrtf(1.0f + (float)cnt[t]);
        }
    }
    if (b == NB - 1 && t == 0) offs[N] = E;
    for (int i = lo + t; i < hi; i += blockDim.x) {
        unsigned e = ebuf[i];
        int l = e >> 26;
        int p = lo + exc[l] + atomicAdd(&cur[l], 1);
        csr[p] = (int)(e & 0x03FFFFFFu);
    }
}

// ---------------------------------------------------------------------------
// Weight pre-transform: W[K][Nc] fp32 -> Wh_t/Wl_t [Nc][K] bf16 (split hi/lo)
// ---------------------------------------------------------------------------
__device__ __forceinline__ unsigned short bf16_rne(float x) {
    unsigned u = __float_as_uint(x);
    return (unsigned short)((u + 0x7fff + ((u >> 16) & 1)) >> 16);
}

__device__ __forceinline__ void convW_one(const float* W, unsigned short* Ht,
                                          unsigned short* Lt, int K, int Nc, int idx) {
    if (idx >= K * Nc) return;
    int k = idx / Nc, n = idx % Nc;
    float a = W[idx];
    unsigned u = __float_as_uint(a);
    unsigned short hi = (unsigned short)(u >> 16);          // truncation
    float hf = __uint_as_float(u & 0xffff0000u);
    unsigned short lo = bf16_rne(a - hf);
    Ht[(long long)n * K + k] = hi;
    Lt[(long long)n * K + k] = lo;
}

__global__ void convW_kernel(const float* __restrict__ W1, unsigned short* __restrict__ H1,
                             unsigned short* __restrict__ L1, int K1, int N1, int nb1,
                             const float* __restrict__ W2, unsigned short* __restrict__ H2,
                             unsigned short* __restrict__ L2, int K2, int N2) {
    if ((int)blockIdx.x < nb1) {
        convW_one(W1, H1, L1, K1, N1, blockIdx.x * blockDim.x + threadIdx.x);
    } else {
        convW_one(W2, H2, L2, K2, N2, (blockIdx.x - nb1) * blockDim.x + threadIdx.x);
    }
}

// ---------------------------------------------------------------------------
// Split-bf16 MFMA GEMM: C[M,NCOL] = A[M,K]fp32 @ B[K,NCOL]fp32
// BM=64, 4 waves x one 16-row tile. A staged via LDS, double-buffered.
// ---------------------------------------------------------------------------
template <int NCOL, int K, typename CT>
__launch_bounds__(256)
__global__ void mfma_gemm_kernel(const float* __restrict__ A,
                                 const unsigned short* __restrict__ Bh,
                                 const unsigned short* __restrict__ Bl,
                                 CT* __restrict__ C, int M) {
    constexpr int NCB = NCOL / 16;   // 8 (GEMM1) or 4 (GEMM2)
    constexpr int BM  = 64;
    constexpr int AST = 36;          // LDS row stride in floats
    __shared__ float As[2][BM * AST];

    const int tid  = threadIdx.x;
    const int wave = tid >> 6;
    const int lane = tid & 63;
    const int n15  = lane & 15;
    const int q    = lane >> 4;
    const int row0 = blockIdx.x * BM;

    floatx4 acc[NCB];
#pragma unroll
    for (int c = 0; c < NCB; ++c) acc[c] = (floatx4){0.f, 0.f, 0.f, 0.f};

    auto stage = [&](int buf, int kc) {
#pragma unroll
        for (int it = 0; it < BM * 8 / 256; ++it) {   // BM*32 floats = BM*8 float4
            int f  = it * 256 + tid;
            int r  = f >> 3;
            int c4 = (f & 7) * 4;
            int gr = row0 + r;
            if (gr >= M) gr = M - 1;
            float4 v = *(const float4*)&A[(long long)gr * K + kc + c4];
            *(float4*)&As[buf][r * AST + c4] = v;
        }
    };

    stage(0, 0);
    __syncthreads();

    int buf = 0;
    for (int kc = 0; kc < K; kc += 32, buf ^= 1) {
        if (kc + 32 < K) stage(buf ^ 1, kc + 32);

        short8 ah, al;
        {
            const float* p = &As[buf][(wave * 16 + n15) * AST + q * 8];
            float4 a0 = *(const float4*)p;
            float4 a1 = *(const float4*)(p + 4);
            float av[8] = {a0.x, a0.y, a0.z, a0.w, a1.x, a1.y, a1.z, a1.w};
#pragma unroll
            for (int j = 0; j < 8; ++j) {
                unsigned u = __float_as_uint(av[j]);
                ah[j] = (short)(u >> 16);
                float hf = __uint_as_float(u & 0xffff0000u);
                al[j] = (short)bf16_rne(av[j] - hf);
            }
        }

#pragma unroll
        for (int cb = 0; cb < NCB; ++cb) {
            long long boff = (long long)(cb * 16 + n15) * K + kc + q * 8;
            short8 bh = *(const short8*)&Bh[boff];
            short8 bl = *(const short8*)&Bl[boff];
            acc[cb] = __builtin_amdgcn_mfma_f32_16x16x32_bf16(ah, bh, acc[cb], 0, 0, 0);
            acc[cb] = __builtin_amdgcn_mfma_f32_16x16x32_bf16(al, bh, acc[cb], 0, 0, 0);
            acc[cb] = __builtin_amdgcn_mfma_f32_16x16x32_bf16(ah, bl, acc[cb], 0, 0, 0);
        }
        __syncthreads();
    }

    // C/D layout: col = cb*16 + n15, row-in-tile = q*4 + reg
#pragma unroll
    for (int cb = 0; cb < NCB; ++cb) {
        int col = cb * 16 + n15;
#pragma unroll
        for (int r = 0; r < 4; ++r) {
            int gr = row0 + wave * 16 + q * 4 + r;
            if (gr < M) C[(long long)gr * NCOL + col] = (CT)acc[cb][r];
        }
    }
}

// ---------------------------------------------------------------------------
// Gather aggregation, fp16 h, 8 channels/lane, 8-edge unroll, w recomputed:
// out[n][:] = (h[n]*dinv[n]^2 + sum_e h[src]*dinv[src]*dinv[n]) + bias (,relu)
// ---------------------------------------------------------------------------
template <int F, int RELU>
__launch_bounds__(256)
__global__ void gatherh_kernel(const _Float16* __restrict__ h, const int* __restrict__ csr,
                               const int* __restrict__ offs, const float* __restrict__ dinv,
                               const float* __restrict__ bias, float* __restrict__ out, int N) {
    constexpr int L = F / 8;            // lanes per node
    constexpr int NPB = 256 / L;        // nodes per block
    const int n = blockIdx.x * NPB + threadIdx.x / L;
    const int c8 = (threadIdx.x % L) * 8;
    if (n >= N) return;

    const float di = dinv[n];
    half8v hs = *(const half8v*)&h[(long long)n * F + c8];
    float acc[8];
    const float sd = di * di;
#pragma unroll
    for (int j = 0; j < 8; ++j) acc[j] = (float)hs[j] * sd;

    int j = offs[n];
    const int end = offs[n + 1];
    for (; j + 7 < end; j += 8) {
        int s[8];
        float ws[8];
        half8v v[8];
#pragma unroll
        for (int u = 0; u < 8; ++u) s[u] = csr[j + u];
#pragma unroll
        for (int u = 0; u < 8; ++u) ws[u] = dinv[s[u]];
#pragma unroll
        for (int u = 0; u < 8; ++u) v[u] = *(const half8v*)&h[(long long)s[u] * F + c8];
#pragma unroll
        for (int u = 0; u < 8; ++u) {
            float w = ws[u] * di;
#pragma unroll
            for (int t = 0; t < 8; ++t) acc[t] = fmaf((float)v[u][t], w, acc[t]);
        }
    }
    for (; j < end; ++j) {
        int s = csr[j];
        float w = dinv[s] * di;
        half8v v = *(const half8v*)&h[(long long)s * F + c8];
#pragma unroll
        for (int t = 0; t < 8; ++t) acc[t] = fmaf((float)v[t], w, acc[t]);
    }

    float4 b0 = *(const float4*)&bias[c8];
    float4 b1 = *(const float4*)&bias[c8 + 4];
    float bb[8] = {b0.x, b0.y, b0.z, b0.w, b1.x, b1.y, b1.z, b1.w};
#pragma unroll
    for (int t = 0; t < 8; ++t) {
        acc[t] += bb[t];
        if (RELU) acc[t] = fmaxf(acc[t], 0.f);
    }
    float* o = &out[(long long)n * F + c8];
    *(float4*)o       = make_float4(acc[0], acc[1], acc[2], acc[3]);
    *(float4*)(o + 4) = make_float4(acc[4], acc[5], acc[6], acc[7]);
}

extern "C" void kernel_launch(void* const* d_in, const int* in_sizes, int n_in,
                              void* d_out, int out_size, void* d_ws, size_t ws_size,
                              hipStream_t stream) {
    const float* x  = (const float*)d_in[0];
    const int*   ei = (const int*)d_in[1];
    const float* W1 = (const float*)d_in[2];
    const float* b1 = (const float*)d_in[3];
    const float* W2 = (const float*)d_in[4];
    const float* b2 = (const float*)d_in[5];
    float* out = (float*)d_out;

    const int IN_CH = 256, HID = 128, OUT = 64;
    const int N = in_sizes[0] / IN_CH;     // 50000
    const int E = in_sizes[1] / 2;         // 800000
    const int NB = (N + BUCK - 1) / BUCK;  // 782 buckets (< 1024)
    const int chunk = (E + NBLK - 1) / NBLK;

    char* w = (char*)d_ws;
    size_t off_b = 0;
    auto alloc = [&](size_t bytes) { void* p = w + off_b; off_b = (off_b + bytes + 255) & ~(size_t)255; return p; };
    int*   flag   = (int*)alloc(256);
    int*   hist2  = (int*)alloc((size_t)NBLK * NB * 4);
    int*   start2 = (int*)alloc((size_t)NBLK * NB * 4);
    int*   bbase  = (int*)alloc((size_t)(NB + 1) * 4);
    int*   offs   = (int*)alloc((size_t)(N + 1) * 4);
    float* dinv   = (float*)alloc((size_t)N * 4);
    unsigned* ebuf = (unsigned*)alloc((size_t)E * 4);
    int*   csr    = (int*)alloc((size_t)E * 4);
    unsigned short* W1h = (unsigned short*)alloc((size_t)IN_CH * HID * 2);
    unsigned short* W1l = (unsigned short*)alloc((size_t)IN_CH * HID * 2);
    unsigned short* W2h = (unsigned short*)alloc((size_t)HID * OUT * 2);
    unsigned short* W2l = (unsigned short*)alloc((size_t)HID * OUT * 2);
    _Float16* h1  = (_Float16*)alloc((size_t)N * HID * 2); // fp16; reused as h2
    float* agg1   = (float*)alloc((size_t)N * HID * 4);    // fp32
    _Float16* h2  = h1;

    const int T = 256;
    detect64_kernel<<<1, 256, 0, stream>>>(ei, flag);
    hist2_kernel<<<NBLK, T, 0, stream>>>(ei, flag, hist2, E, NB, chunk);
    bscan2_kernel<<<1, 1024, 0, stream>>>(hist2, bbase, start2, NB, E);
    scatter2_kernel<<<NBLK, T, 0, stream>>>(ei, flag, start2, ebuf, E, NB, chunk);
    csrbuild_kernel<<<NB, T, 0, stream>>>(ebuf, bbase, offs, dinv, csr, N, NB, E);

    {
        int nb1 = (IN_CH * HID + T - 1) / T;
        int nb2 = (HID * OUT + T - 1) / T;
        convW_kernel<<<nb1 + nb2, T, 0, stream>>>(W1, W1h, W1l, IN_CH, HID, nb1,
                                                  W2, W2h, W2l, HID, OUT);
    }

    // GEMM1: h1[N,128](fp16) = x[N,256] @ W1
    mfma_gemm_kernel<128, 256, _Float16><<<(N + 63) / 64, 256, 0, stream>>>(x, W1h, W1l, h1, N);
    // layer-1 aggregation (fp16 gather, fused self-loop + bias + relu) -> agg1 (fp32)
    gatherh_kernel<128, 1><<<(N * 16 + 255) / 256, 256, 0, stream>>>(h1, csr, offs, dinv, b1, agg1, N);
    // GEMM2: h2[N,64](fp16) = agg1[N,128] @ W2
    mfma_gemm_kernel<64, 128, _Float16><<<(N + 63) / 64, 256, 0, stream>>>(agg1, W2h, W2l, h2, N);
    // layer-2 aggregation (fp16 gather, fused self-loop + bias) -> out (fp32)
    gatherh_kernel<64, 0><<<(N * 8 + 255) / 256, 256, 0, stream>>>(h2, csr, offs, dinv, b2, out, N);
}

// Round 8
// 242.145 us; speedup vs baseline: 1.8561x; 1.1865x over previous
//
#include <hip/hip_runtime.h>

// ---------------------------------------------------------------------------
// GCN encoder: out = GCNConv2( relu(GCNConv1(x)) )
// R7: GEMM rebuilt — single fp16 MFMA (no split-bf16), async global_load_lds
// staging (BM=128, BK=64, double-buffered, XOR-swizzled LDS units).
// CSR build (R6, zero global atomics) and fp16 gathers (R5/R6) unchanged.
// ---------------------------------------------------------------------------

typedef __attribute__((ext_vector_type(4))) float floatx4;
typedef _Float16 __attribute__((ext_vector_type(8))) half8v;

#define BUCK_SH 6
#define BUCK    64           // dsts per bucket
#define NBLK    256          // blocks for hist2/scatter2

#define AS1(p) ((const __attribute__((address_space(1))) void*)(p))
#define AS3(p) ((__attribute__((address_space(3))) void*)(p))

// edge_index may arrive as int64 (reference dtype) or int32 (harness contract).
__global__ void detect64_kernel(const int* __restrict__ ei, int* __restrict__ flag) {
    __shared__ int nz;
    if (threadIdx.x == 0) nz = 0;
    __syncthreads();
    if (ei[2 * threadIdx.x + 1] != 0) atomicOr(&nz, 1);
    __syncthreads();
    if (threadIdx.x == 0) *flag = (nz == 0) ? 1 : 0;
}

__device__ __forceinline__ int edge_id(const int* __restrict__ ei, int is64, long long pos) {
    return is64 ? ei[2 * pos] : ei[(int)pos];
}

// ---- per-block bucket histogram -> hist2[blk][NB] (no global atomics) ------
__global__ void hist2_kernel(const int* __restrict__ ei, const int* __restrict__ flag,
                             int* __restrict__ hist2, int E, int NB, int chunk) {
    __shared__ int h[1024];
    const int t = threadIdx.x;
    for (int i = t; i < NB; i += blockDim.x) h[i] = 0;
    __syncthreads();
    const int is64 = *flag;
    const int lo = blockIdx.x * chunk;
    const int hi = min(E, lo + chunk);
    for (int e = lo + t; e < hi; e += blockDim.x) {
        int d = edge_id(ei, is64, (long long)E + e);
        atomicAdd(&h[d >> BUCK_SH], 1);
    }
    __syncthreads();
    for (int i = t; i < NB; i += blockDim.x) hist2[(long long)blockIdx.x * NB + i] = h[i];
}

// ---- single block: column sums -> bucket scan -> bbase + start2 ------------
__global__ void bscan2_kernel(const int* __restrict__ hist2, int* __restrict__ bbase,
                              int* __restrict__ start2, int NB, int E) {
    __shared__ int sm[1024];
    const int t = threadIdx.x;           // t = bucket id
    int col = 0;
    if (t < NB)
        for (int b = 0; b < NBLK; ++b) col += hist2[(long long)b * NB + t];
    sm[t] = col;
    __syncthreads();
    for (int s = 1; s < 1024; s <<= 1) {
        int u = (t >= s) ? sm[t - s] : 0;
        __syncthreads();
        sm[t] += u;
        __syncthreads();
    }
    int excl = sm[t] - col;
    if (t < NB) {
        bbase[t] = excl;
        int run = excl;
        for (int b = 0; b < NBLK; ++b) {
            start2[(long long)b * NB + t] = run;
            run += hist2[(long long)b * NB + t];
        }
    }
    if (t == 0) bbase[NB] = E;
}

// ---- scatter: LDS cursors only, packed record src | (dlocal<<26) -----------
__global__ void scatter2_kernel(const int* __restrict__ ei, const int* __restrict__ flag,
                                const int* __restrict__ start2, unsigned* __restrict__ ebuf,
                                int E, int NB, int chunk) {
    __shared__ int hcur[1024];
    const int t = threadIdx.x;
    for (int i = t; i < NB; i += blockDim.x)
        hcur[i] = start2[(long long)blockIdx.x * NB + i];
    __syncthreads();
    const int is64 = *flag;
    const int lo = blockIdx.x * chunk;
    const int hi = min(E, lo + chunk);
    for (int e = lo + t; e < hi; e += blockDim.x) {
        int s = edge_id(ei, is64, e);
        int d = edge_id(ei, is64, (long long)E + e);
        int pos = atomicAdd(&hcur[d >> BUCK_SH], 1);
        ebuf[pos] = (unsigned)s | ((unsigned)(d & (BUCK - 1)) << 26);
    }
}

// ---- per-bucket exact CSR build: offs, dinv, csr(src only) -----------------
__global__ void csrbuild_kernel(const unsigned* __restrict__ ebuf, const int* __restrict__ bbase,
                                int* __restrict__ offs, float* __restrict__ dinv,
                                int* __restrict__ csr, int N, int NB, int E) {
    __shared__ int cnt[BUCK], exc[BUCK], cur[BUCK];
    const int b = blockIdx.x;
    const int t = threadIdx.x;
    if (t < BUCK) { cnt[t] = 0; cur[t] = 0; }
    __syncthreads();
    const int lo = bbase[b], hi = bbase[b + 1];
    for (int i = lo + t; i < hi; i += blockDim.x)
        atomicAdd(&cnt[ebuf[i] >> 26], 1);
    __syncthreads();
    if (t == 0) {
        int run = 0;
        for (int l = 0; l < BUCK; ++l) { exc[l] = run; run += cnt[l]; }
    }
    __syncthreads();
    if (t < BUCK) {
        int n = b * BUCK + t;
        if (n < N) {
            offs[n] = lo + exc[t];
            dinv[n] = rsqrtf(1.0f + (float)cnt[t]);
        }
    }
    if (b == NB - 1 && t == 0) offs[N] = E;
    for (int i = lo + t; i < hi; i += blockDim.x) {
        unsigned e = ebuf[i];
        int l = e >> 26;
        int p = lo + exc[l] + atomicAdd(&cur[l], 1);
        csr[p] = (int)(e & 0x03FFFFFFu);
    }
}

// ---------------------------------------------------------------------------
// Weight pre-transform: W[K][Nc] fp32 -> Wt [Nc][K] fp16 (single plane)
// ---------------------------------------------------------------------------
__device__ __forceinline__ void convW_one(const float* W, _Float16* Wt, int K, int Nc, int idx) {
    if (idx >= K * Nc) return;
    int k = idx / Nc, n = idx % Nc;
    Wt[(long long)n * K + k] = (_Float16)W[idx];
}

__global__ void convW_kernel(const float* __restrict__ W1, _Float16* __restrict__ T1,
                             int K1, int N1, int nb1,
                             const float* __restrict__ W2, _Float16* __restrict__ T2,
                             int K2, int N2) {
    if ((int)blockIdx.x < nb1) {
        convW_one(W1, T1, K1, N1, blockIdx.x * blockDim.x + threadIdx.x);
    } else {
        convW_one(W2, T2, K2, N2, (blockIdx.x - nb1) * blockDim.x + threadIdx.x);
    }
}

// ---------------------------------------------------------------------------
// fp16 MFMA GEMM: C[M,NCOL](fp16) = A[M,K](fp32) @ B[K,NCOL]
// B pre-transposed fp16 [NCOL][K] (L2-resident). BM=128, BK=64, 4 waves,
// RT=2 row-tiles/wave. A staged fp32 via async global_load_lds (width 16),
// double-buffered, XOR-swizzled 16B units for conflict-free ds_read_b128.
// ---------------------------------------------------------------------------
template <int NCOL, int K>
__launch_bounds__(256)
__global__ void gemm_f16_kernel(const float* __restrict__ A,
                                const _Float16* __restrict__ Bt,
                                _Float16* __restrict__ C, int M) {
    constexpr int NCB = NCOL / 16;
    constexpr int BM = 128, BK = 64;
    constexpr int NC = K / BK;                 // 4 (GEMM1) / 2 (GEMM2)
    constexpr int UNITS = BM * BK / 4;         // 16B units per chunk = 2048
    __shared__ float As[2][BM * BK];           // 2 x 32 KB

    const int tid  = threadIdx.x;
    const int wave = tid >> 6;
    const int lane = tid & 63;
    const int n15  = lane & 15;
    const int q    = lane >> 4;
    const int row0 = blockIdx.x * BM;

    floatx4 acc[2][NCB];
#pragma unroll
    for (int rt = 0; rt < 2; ++rt)
#pragma unroll
        for (int c = 0; c < NCB; ++c) acc[rt][c] = (floatx4){0.f, 0.f, 0.f, 0.f};

    // async stage of a BM x BK fp32 chunk. LDS unit g holds global col-unit
    // u = (g&15) ^ (r&15) of row r = g>>4  (XOR swizzle, bank-conflict-free).
    auto stage = [&](int buf, int kc) {
#pragma unroll
        for (int j = 0; j < UNITS / 256; ++j) {
            int g = j * 256 + tid;
            int r = g >> 4;
            int u = (g & 15) ^ (r & 15);
            int gr = row0 + r;
            if (gr >= M) gr = M - 1;
            const float* gp = &A[(long long)gr * K + kc + u * 4];
            float* lp = &As[buf][g * 4];
            __builtin_amdgcn_global_load_lds(AS1(gp), AS3(lp), 16, 0, 0);
        }
    };

    stage(0, 0);
    __syncthreads();

#pragma unroll
    for (int c = 0; c < NC; ++c) {
        if (c + 1 < NC) stage((c + 1) & 1, (c + 1) * BK);   // async prefetch
        const int buf = c & 1;
#pragma unroll
        for (int ks = 0; ks < 2; ++ks) {                    // two K=32 sub-steps
            half8v af[2];
#pragma unroll
            for (int rt = 0; rt < 2; ++rt) {
                const int R = wave * 32 + rt * 16 + n15;
                const int u0 = ks * 8 + q * 2;
                const int p0 = (u0)     ^ (R & 15);
                const int p1 = (u0 + 1) ^ (R & 15);
                float4 f0 = *(const float4*)&As[buf][R * BK + p0 * 4];
                float4 f1 = *(const float4*)&As[buf][R * BK + p1 * 4];
                af[rt][0] = (_Float16)f0.x; af[rt][1] = (_Float16)f0.y;
                af[rt][2] = (_Float16)f0.z; af[rt][3] = (_Float16)f0.w;
                af[rt][4] = (_Float16)f1.x; af[rt][5] = (_Float16)f1.y;
                af[rt][6] = (_Float16)f1.z; af[rt][7] = (_Float16)f1.w;
            }
#pragma unroll
            for (int cb = 0; cb < NCB; ++cb) {
                const _Float16* bp = &Bt[(long long)(cb * 16 + n15) * K + c * BK + ks * 32 + q * 8];
                half8v bf = *(const half8v*)bp;
                acc[0][cb] = __builtin_amdgcn_mfma_f32_16x16x32_f16(af[0], bf, acc[0][cb], 0, 0, 0);
                acc[1][cb] = __builtin_amdgcn_mfma_f32_16x16x32_f16(af[1], bf, acc[1][cb], 0, 0, 0);
            }
        }
        if (c + 1 < NC) __syncthreads();
    }

    // C/D layout: col = cb*16 + n15, row-in-tile = q*4 + reg
#pragma unroll
    for (int rt = 0; rt < 2; ++rt) {
#pragma unroll
        for (int cb = 0; cb < NCB; ++cb) {
            int col = cb * 16 + n15;
#pragma unroll
            for (int r = 0; r < 4; ++r) {
                int gr = row0 + wave * 32 + rt * 16 + q * 4 + r;
                if (gr < M) C[(long long)gr * NCOL + col] = (_Float16)acc[rt][cb][r];
            }
        }
    }
}

// ---------------------------------------------------------------------------
// Gather aggregation, fp16 h, 8 channels/lane, 8-edge unroll, w recomputed:
// out[n][:] = (h[n]*dinv[n]^2 + sum_e h[src]*dinv[src]*dinv[n]) + bias (,relu)
// ---------------------------------------------------------------------------
template <int F, int RELU>
__launch_bounds__(256)
__global__ void gatherh_kernel(const _Float16* __restrict__ h, const int* __restrict__ csr,
                               const int* __restrict__ offs, const float* __restrict__ dinv,
                               const float* __restrict__ bias, float* __restrict__ out, int N) {
    constexpr int L = F / 8;            // lanes per node
    constexpr int NPB = 256 / L;        // nodes per block
    const int n = blockIdx.x * NPB + threadIdx.x / L;
    const int c8 = (threadIdx.x % L) * 8;
    if (n >= N) return;

    const float di = dinv[n];
    half8v hs = *(const half8v*)&h[(long long)n * F + c8];
    float acc[8];
    const float sd = di * di;
#pragma unroll
    for (int j = 0; j < 8; ++j) acc[j] = (float)hs[j] * sd;

    int j = offs[n];
    const int end = offs[n + 1];
    for (; j + 7 < end; j += 8) {
        int s[8];
        float ws[8];
        half8v v[8];
#pragma unroll
        for (int u = 0; u < 8; ++u) s[u] = csr[j + u];
#pragma unroll
        for (int u = 0; u < 8; ++u) ws[u] = dinv[s[u]];
#pragma unroll
        for (int u = 0; u < 8; ++u) v[u] = *(const half8v*)&h[(long long)s[u] * F + c8];
#pragma unroll
        for (int u = 0; u < 8; ++u) {
            float w = ws[u] * di;
#pragma unroll
            for (int t = 0; t < 8; ++t) acc[t] = fmaf((float)v[u][t], w, acc[t]);
        }
    }
    for (; j < end; ++j) {
        int s = csr[j];
        float w = dinv[s] * di;
        half8v v = *(const half8v*)&h[(long long)s * F + c8];
#pragma unroll
        for (int t = 0; t < 8; ++t) acc[t] = fmaf((float)v[t], w, acc[t]);
    }

    float4 b0 = *(const float4*)&bias[c8];
    float4 b1 = *(const float4*)&bias[c8 + 4];
    float bb[8] = {b0.x, b0.y, b0.z, b0.w, b1.x, b1.y, b1.z, b1.w};
#pragma unroll
    for (int t = 0; t < 8; ++t) {
        acc[t] += bb[t];
        if (RELU) acc[t] = fmaxf(acc[t], 0.f);
    }
    float* o = &out[(long long)n * F + c8];
    *(float4*)o       = make_float4(acc[0], acc[1], acc[2], acc[3]);
    *(float4*)(o + 4) = make_float4(acc[4], acc[5], acc[6], acc[7]);
}

extern "C" void kernel_launch(void* const* d_in, const int* in_sizes, int n_in,
                              void* d_out, int out_size, void* d_ws, size_t ws_size,
                              hipStream_t stream) {
    const float* x  = (const float*)d_in[0];
    const int*   ei = (const int*)d_in[1];
    const float* W1 = (const float*)d_in[2];
    const float* b1 = (const float*)d_in[3];
    const float* W2 = (const float*)d_in[4];
    const float* b2 = (const float*)d_in[5];
    float* out = (float*)d_out;

    const int IN_CH = 256, HID = 128, OUT = 64;
    const int N = in_sizes[0] / IN_CH;     // 50000
    const int E = in_sizes[1] / 2;         // 800000
    const int NB = (N + BUCK - 1) / BUCK;  // 782 buckets (< 1024)
    const int chunk = (E + NBLK - 1) / NBLK;

    char* w = (char*)d_ws;
    size_t off_b = 0;
    auto alloc = [&](size_t bytes) { void* p = w + off_b; off_b = (off_b + bytes + 255) & ~(size_t)255; return p; };
    int*   flag   = (int*)alloc(256);
    int*   hist2  = (int*)alloc((size_t)NBLK * NB * 4);
    int*   start2 = (int*)alloc((size_t)NBLK * NB * 4);
    int*   bbase  = (int*)alloc((size_t)(NB + 1) * 4);
    int*   offs   = (int*)alloc((size_t)(N + 1) * 4);
    float* dinv   = (float*)alloc((size_t)N * 4);
    unsigned* ebuf = (unsigned*)alloc((size_t)E * 4);
    int*   csr    = (int*)alloc((size_t)E * 4);
    _Float16* W1t = (_Float16*)alloc((size_t)IN_CH * HID * 2);
    _Float16* W2t = (_Float16*)alloc((size_t)HID * OUT * 2);
    _Float16* h1  = (_Float16*)alloc((size_t)N * HID * 2); // fp16; reused as h2
    float* agg1   = (float*)alloc((size_t)N * HID * 4);    // fp32
    _Float16* h2  = h1;

    const int T = 256;
    detect64_kernel<<<1, 256, 0, stream>>>(ei, flag);
    hist2_kernel<<<NBLK, T, 0, stream>>>(ei, flag, hist2, E, NB, chunk);
    bscan2_kernel<<<1, 1024, 0, stream>>>(hist2, bbase, start2, NB, E);
    scatter2_kernel<<<NBLK, T, 0, stream>>>(ei, flag, start2, ebuf, E, NB, chunk);
    csrbuild_kernel<<<NB, T, 0, stream>>>(ebuf, bbase, offs, dinv, csr, N, NB, E);

    {
        int nb1 = (IN_CH * HID + T - 1) / T;
        int nb2 = (HID * OUT + T - 1) / T;
        convW_kernel<<<nb1 + nb2, T, 0, stream>>>(W1, W1t, IN_CH, HID, nb1,
                                                  W2, W2t, HID, OUT);
    }

    // GEMM1: h1[N,128](fp16) = x[N,256] @ W1
    gemm_f16_kernel<128, 256><<<(N + 127) / 128, 256, 0, stream>>>(x, W1t, h1, N);
    // layer-1 aggregation (fp16 gather, fused self-loop + bias + relu) -> agg1 (fp32)
    gatherh_kernel<128, 1><<<(N * 16 + 255) / 256, 256, 0, stream>>>(h1, csr, offs, dinv, b1, agg1, N);
    // GEMM2: h2[N,64](fp16) = agg1[N,128] @ W2
    gemm_f16_kernel<64, 128><<<(N + 127) / 128, 256, 0, stream>>>(agg1, W2t, h2, N);
    // layer-2 aggregation (fp16 gather, fused self-loop + bias) -> out (fp32)
    gatherh_kernel<64, 0><<<(N * 8 + 255) / 256, 256, 0, stream>>>(h2, csr, offs, dinv, b2, out, N);
}